// Round 1
// baseline (707.500 us; speedup 1.0000x reference)
//
#include <hip/hip_runtime.h>
#include <hip/hip_bf16.h>

// Problem constants
#define BB 8
#define QQ 4
#define HH 4096
#define NH 32
#define NKV 8
#define GG 4
#define HD 128
#define SS 4096
#define CAP 4100
#define ROWS 32            // B*Q
#define NQCOL 4096         // NH*HD
#define NKCOL 1024         // NKV*HD
#define NTOTC 6144         // NQCOL + 2*NKCOL
#define KSPLIT 16
#define KCHUNK 256         // HH / KSPLIT
#define SCALE 0.08838834764831845f
#define NSPLIT 9           // 9*512 = 4608 >= 4100
#define NEG_BIG 1e30f

// ---------------------------------------------------------------------------
// Kernel A/E: 32-row GEMM, K-split partials.
// y[r][c] = sum_k x[r][k] * W[k][c], written as partials per k-block.
// x rows are wave-uniform -> scalar loads; W loads coalesced across lanes.
// ---------------------------------------------------------------------------
__global__ __launch_bounds__(256) void gemm32_part(
    const float* __restrict__ x, const float* __restrict__ W0,
    const float* __restrict__ W1, const float* __restrict__ W2,
    int n0, int n01, int ntot, float* __restrict__ part) {
  int nblk = ntot >> 8;
  int cb = blockIdx.x % nblk;
  int kb = blockIdx.x / nblk;
  int c = (cb << 8) + threadIdx.x;
  int k0 = kb << 8;

  const float* W;
  int ldw, wc;
  if (c < n0)       { W = W0; ldw = n0;         wc = c; }
  else if (c < n01) { W = W1; ldw = n01 - n0;   wc = c - n0; }
  else              { W = W2; ldw = ntot - n01; wc = c - n01; }

  const float* wp = W + (size_t)k0 * ldw + wc;
  const float* xp = x + k0;

  float acc[ROWS];
#pragma unroll
  for (int r = 0; r < ROWS; ++r) acc[r] = 0.f;

  for (int kk = 0; kk < KCHUNK; kk += 4) {
    float w0 = wp[0];
    float w1 = wp[ldw];
    float w2 = wp[2 * ldw];
    float w3 = wp[3 * ldw];
    wp += (size_t)4 * ldw;
#pragma unroll
    for (int r = 0; r < ROWS; ++r) {
      const float4 xv = *(const float4*)(xp + (r << 12) + kk);
      acc[r] = fmaf(xv.x, w0, acc[r]);
      acc[r] = fmaf(xv.y, w1, acc[r]);
      acc[r] = fmaf(xv.z, w2, acc[r]);
      acc[r] = fmaf(xv.w, w3, acc[r]);
    }
  }
#pragma unroll
  for (int r = 0; r < ROWS; ++r) part[(size_t)((kb << 5) + r) * ntot + c] = acc[r];
}

// ---------------------------------------------------------------------------
// Kernel B: reduce K-split partials + RoPE (pairwise d, d+64) + scatter k/v
// into the KV caches; q (scaled) to q_buf.
// Thread space: [0,81920): rope pairs (q then k), [81920,114688): v singles.
// ---------------------------------------------------------------------------
__global__ __launch_bounds__(256) void rope_reduce_scatter(
    const float* __restrict__ ypart, const float* __restrict__ cosb,
    const float* __restrict__ sinb, const int* __restrict__ cache_lens,
    float* __restrict__ q_buf, float* __restrict__ K_cache,
    float* __restrict__ V_cache) {
  int idx = blockIdx.x * 256 + threadIdx.x;
  if (idx < 81920) {                       // rope pairs: 32 rows * 2560 pairs
    int r = idx / 2560;
    int o = idx % 2560;
    int b = r >> 2, qp = r & 3;
    int c1;
    int d;
    bool is_q;
    if (o < 2048) {                        // q pairs
      int h = o >> 6; d = o & 63;
      c1 = h * HD + d;
      is_q = true;
    } else {                               // k pairs
      int ok = o - 2048;
      int kvh = ok >> 6; d = ok & 63;
      c1 = NQCOL + kvh * HD + d;
      is_q = false;
    }
    int c2 = c1 + 64;
    float s1 = 0.f, s2 = 0.f;
#pragma unroll
    for (int kb = 0; kb < KSPLIT; ++kb) {
      s1 += ypart[(size_t)((kb << 5) + r) * NTOTC + c1];
      s2 += ypart[(size_t)((kb << 5) + r) * NTOTC + c2];
    }
    float cv = cosb[(r << 7) + d];
    float sv = sinb[(r << 7) + d];
    float o1 = s1 * cv - s2 * sv;          // d < 64: rot = -x[d+64]
    float o2 = s2 * cv + s1 * sv;          // d >= 64: rot = +x[d-64]
    if (is_q) {
      q_buf[(size_t)r * NQCOL + c1] = o1 * SCALE;
      q_buf[(size_t)r * NQCOL + c2] = o2 * SCALE;
    } else {
      int kvh = (c1 - NQCOL) >> 7;
      int pos = cache_lens[b] + qp;
      size_t base = ((size_t)(b * CAP + pos) * NKV + kvh) * HD;
      K_cache[base + d] = o1;
      K_cache[base + d + 64] = o2;
    }
  } else {                                 // v singles: 32 rows * 1024 cols
    int vi = idx - 81920;
    int r = vi >> 10;
    int cc = vi & 1023;
    int b = r >> 2, qp = r & 3;
    int c = NQCOL + NKCOL + cc;
    float s = 0.f;
#pragma unroll
    for (int kb = 0; kb < KSPLIT; ++kb)
      s += ypart[(size_t)((kb << 5) + r) * NTOTC + c];
    int kvh = cc >> 7, d = cc & 127;
    int pos = cache_lens[b] + qp;
    V_cache[((size_t)(b * CAP + pos) * NKV + kvh) * HD + d] = s;
  }
}

// ---------------------------------------------------------------------------
// Kernel C: flash-decode attention partials.
// grid: 64 (b,kv) groups x NSPLIT seq-splits. block: 256 thr = 4 waves.
// Each wave handles 128 positions of the 512-position split.
// Phase 1: lane = position (2 per lane), dot vs 16 q's; softmax per wave.
// Phase 2: lane = dim pair, PV accumulate via p staged in LDS.
// ---------------------------------------------------------------------------
__global__ __launch_bounds__(256) void attn_partial(
    const float* __restrict__ q_buf, const float* __restrict__ K_cache,
    const float* __restrict__ V_cache, const int* __restrict__ cache_lens,
    float* __restrict__ part_o, float* __restrict__ part_m,
    float* __restrict__ part_l) {
  __shared__ float q_lds[16][HD];
  __shared__ float smem[4][16][128];   // p (phase 1/2), then o (merge)
  __shared__ float m_lds[4][16];
  __shared__ float l_lds[4][16];

  int g = blockIdx.x & 63;
  int split = blockIdx.x >> 6;
  int b = g >> 3, kv = g & 7;
  int t = threadIdx.x, w = t >> 6, lane = t & 63;

  // load q tile (already scaled)
  for (int i = t; i < 2048; i += 256) {
    int qi = i >> 7, d = i & 127;
    int qp = qi >> 2, gi = qi & 3;
    q_lds[qi][d] = q_buf[(size_t)((b << 2) + qp) * NQCOL + (((kv << 2) + gi) << 7) + d];
  }
  __syncthreads();

  int cl = cache_lens[b];
  int cl3 = cl + 3;
  int jb = split * 512 + w * 128;
  int j0 = jb + lane, j1 = jb + 64 + lane;
  int jc0 = min(j0, cl3), jc1 = min(j1, cl3);
  const float* kp0 = K_cache + ((size_t)(b * CAP + jc0) * NKV + kv) * HD;
  const float* kp1 = K_cache + ((size_t)(b * CAP + jc1) * NKV + kv) * HD;

  float sc0[16], sc1[16];
#pragma unroll
  for (int qi = 0; qi < 16; ++qi) { sc0[qi] = 0.f; sc1[qi] = 0.f; }

  for (int d = 0; d < HD; d += 4) {
    const float4 ka = *(const float4*)(kp0 + d);
    const float4 kc = *(const float4*)(kp1 + d);
#pragma unroll
    for (int qi = 0; qi < 16; ++qi) {
      const float4 qv = *(const float4*)&q_lds[qi][d];
      sc0[qi] = fmaf(qv.x, ka.x, sc0[qi]);
      sc0[qi] = fmaf(qv.y, ka.y, sc0[qi]);
      sc0[qi] = fmaf(qv.z, ka.z, sc0[qi]);
      sc0[qi] = fmaf(qv.w, ka.w, sc0[qi]);
      sc1[qi] = fmaf(qv.x, kc.x, sc1[qi]);
      sc1[qi] = fmaf(qv.y, kc.y, sc1[qi]);
      sc1[qi] = fmaf(qv.z, kc.z, sc1[qi]);
      sc1[qi] = fmaf(qv.w, kc.w, sc1[qi]);
    }
  }

  // mask + wave softmax, p -> LDS
  float mreg[16], lreg[16];
#pragma unroll
  for (int qi = 0; qi < 16; ++qi) {
    int qp = qi >> 2;
    float s0 = (j0 <= cl + qp) ? sc0[qi] : -NEG_BIG;
    float s1 = (j1 <= cl + qp) ? sc1[qi] : -NEG_BIG;
    float mm = fmaxf(s0, s1);
#pragma unroll
    for (int off = 32; off > 0; off >>= 1) mm = fmaxf(mm, __shfl_xor(mm, off));
    float e0 = __expf(s0 - mm);
    float e1 = __expf(s1 - mm);
    float ls = e0 + e1;
#pragma unroll
    for (int off = 32; off > 0; off >>= 1) ls += __shfl_xor(ls, off);
    mreg[qi] = mm;
    lreg[qi] = ls;
    smem[w][qi][lane] = e0;
    smem[w][qi][64 + lane] = e1;
  }

  // Phase 2: PV. lane owns dims (2*lane, 2*lane+1)
  float o0[16], o1[16];
#pragma unroll
  for (int qi = 0; qi < 16; ++qi) { o0[qi] = 0.f; o1[qi] = 0.f; }
  int dl = lane << 1;
  const float* vbase = V_cache + ((size_t)b * CAP * NKV + kv) * HD + dl;

  for (int jj = 0; jj < 128; jj += 4) {
    const float2 va = *(const float2*)(vbase + (size_t)min(jb + jj + 0, cl3) * (NKV * HD));
    const float2 vb = *(const float2*)(vbase + (size_t)min(jb + jj + 1, cl3) * (NKV * HD));
    const float2 vc = *(const float2*)(vbase + (size_t)min(jb + jj + 2, cl3) * (NKV * HD));
    const float2 vd = *(const float2*)(vbase + (size_t)min(jb + jj + 3, cl3) * (NKV * HD));
#pragma unroll
    for (int qi = 0; qi < 16; ++qi) {
      const float4 pv = *(const float4*)&smem[w][qi][jj];
      o0[qi] = fmaf(pv.x, va.x, o0[qi]); o1[qi] = fmaf(pv.x, va.y, o1[qi]);
      o0[qi] = fmaf(pv.y, vb.x, o0[qi]); o1[qi] = fmaf(pv.y, vb.y, o1[qi]);
      o0[qi] = fmaf(pv.z, vc.x, o0[qi]); o1[qi] = fmaf(pv.z, vc.y, o1[qi]);
      o0[qi] = fmaf(pv.w, vd.x, o0[qi]); o1[qi] = fmaf(pv.w, vd.y, o1[qi]);
    }
  }

  // per-wave results into LDS (own region only; no cross-wave hazard yet)
#pragma unroll
  for (int qi = 0; qi < 16; ++qi) {
    float2 ov = make_float2(o0[qi], o1[qi]);
    *(float2*)&smem[w][qi][dl] = ov;
  }
  if (lane == 0) {
#pragma unroll
    for (int qi = 0; qi < 16; ++qi) { m_lds[w][qi] = mreg[qi]; l_lds[w][qi] = lreg[qi]; }
  }
  __syncthreads();

  // merge 4 waves -> split partial
  size_t base_out = (size_t)(split * 64 + g) * 16 * 128;
  int base_ml = (split * 64 + g) * 16;
  for (int i = t; i < 2048; i += 256) {
    int qi = i >> 7, d = i & 127;
    float m0 = m_lds[0][qi], m1 = m_lds[1][qi], m2 = m_lds[2][qi], m3 = m_lds[3][qi];
    float M = fmaxf(fmaxf(m0, m1), fmaxf(m2, m3));
    float w0 = __expf(m0 - M), w1 = __expf(m1 - M);
    float w2 = __expf(m2 - M), w3 = __expf(m3 - M);
    float ov = smem[0][qi][d] * w0 + smem[1][qi][d] * w1 +
               smem[2][qi][d] * w2 + smem[3][qi][d] * w3;
    part_o[base_out + qi * 128 + d] = ov;
    if (d == 0) {
      part_m[base_ml + qi] = M;
      part_l[base_ml + qi] = l_lds[0][qi] * w0 + l_lds[1][qi] * w1 +
                             l_lds[2][qi] * w2 + l_lds[3][qi] * w3;
    }
  }
}

// ---------------------------------------------------------------------------
// Kernel D: combine seq-split partials -> attn_out (32 x 4096, head-major)
// ---------------------------------------------------------------------------
__global__ __launch_bounds__(256) void attn_combine(
    const float* __restrict__ part_o, const float* __restrict__ part_m,
    const float* __restrict__ part_l, float* __restrict__ attn_out) {
  int idx = blockIdx.x * 256 + threadIdx.x;  // 131072
  int d = idx & 127;
  int qi = (idx >> 7) & 15;
  int g = idx >> 11;
  int b = g >> 3, kv = g & 7;
  float M = -NEG_BIG;
#pragma unroll
  for (int s = 0; s < NSPLIT; ++s) M = fmaxf(M, part_m[(s * 64 + g) * 16 + qi]);
  float osum = 0.f, L = 0.f;
#pragma unroll
  for (int s = 0; s < NSPLIT; ++s) {
    int ml = (s * 64 + g) * 16 + qi;
    float wgt = __expf(part_m[ml] - M);
    osum += part_o[(size_t)ml * 128 + d] * wgt;
    L += part_l[ml] * wgt;
  }
  int qp = qi >> 2, gi = qi & 3;
  attn_out[(size_t)((b << 2) + qp) * NQCOL + (((kv << 2) + gi) << 7) + d] = osum / L;
}

// ---------------------------------------------------------------------------
// Kernel F: reduce O-proj partials -> d_out
// ---------------------------------------------------------------------------
__global__ __launch_bounds__(256) void reduce_out(
    const float* __restrict__ opart, float* __restrict__ out) {
  int idx = blockIdx.x * 256 + threadIdx.x;  // 131072
  int c = idx & 4095;
  int r = idx >> 12;
  float s = 0.f;
#pragma unroll
  for (int kb = 0; kb < KSPLIT; ++kb)
    s += opart[(size_t)((kb << 5) + r) * NQCOL + c];
  out[idx] = s;
}

extern "C" void kernel_launch(void* const* d_in, const int* in_sizes, int n_in,
                              void* d_out, int out_size, void* d_ws, size_t ws_size,
                              hipStream_t stream) {
  const float* hidden = (const float*)d_in[0];
  const float* cosb   = (const float*)d_in[1];
  const float* sinb   = (const float*)d_in[2];
  const float* Wq     = (const float*)d_in[3];
  const float* Wk     = (const float*)d_in[4];
  const float* Wv     = (const float*)d_in[5];
  const float* Wo     = (const float*)d_in[6];
  float* K_cache      = (float*)d_in[7];
  float* V_cache      = (float*)d_in[8];
  const int* cache_lens = (const int*)d_in[9];
  float* out = (float*)d_out;

  float* ypart   = (float*)d_ws;                         // 16*32*6144
  float* q_buf   = ypart + (size_t)KSPLIT * ROWS * NTOTC; // 32*4096
  float* part_o  = q_buf + (size_t)ROWS * NQCOL;          // 9*64*16*128
  float* part_m  = part_o + (size_t)NSPLIT * 64 * 16 * 128;
  float* part_l  = part_m + (size_t)NSPLIT * 64 * 16;
  float* attn_out = part_l + (size_t)NSPLIT * 64 * 16;    // 32*4096
  float* opart   = attn_out + (size_t)ROWS * NQCOL;       // 16*32*4096

  // A: QKV projection partials
  gemm32_part<<<(NTOTC / 256) * KSPLIT, 256, 0, stream>>>(
      hidden, Wq, Wk, Wv, NQCOL, NQCOL + NKCOL, NTOTC, ypart);
  // B: reduce + RoPE + scatter
  rope_reduce_scatter<<<448, 256, 0, stream>>>(
      ypart, cosb, sinb, cache_lens, q_buf, K_cache, V_cache);
  // C: attention partials
  attn_partial<<<64 * NSPLIT, 256, 0, stream>>>(
      q_buf, K_cache, V_cache, cache_lens, part_o, part_m, part_l);
  // D: combine
  attn_combine<<<512, 256, 0, stream>>>(part_o, part_m, part_l, attn_out);
  // E: O projection partials
  gemm32_part<<<(NQCOL / 256) * KSPLIT, 256, 0, stream>>>(
      attn_out, Wo, Wo, Wo, NQCOL, NQCOL, NQCOL, opart);
  // F: reduce to output
  reduce_out<<<512, 256, 0, stream>>>(opart, out);
}

// Round 4
// 556.437 us; speedup vs baseline: 1.2715x; 1.2715x over previous
//
#include <hip/hip_runtime.h>
#include <hip/hip_bf16.h>

// Problem constants
#define BB 8
#define QQ 4
#define HH 4096
#define NH 32
#define NKV 8
#define GG 4
#define HD 128
#define SS 4096
#define CAP 4100
#define ROWS 32            // B*Q
#define NQCOL 4096         // NH*HD
#define NKCOL 1024         // NKV*HD
#define NTOTC 6144         // NQCOL + 2*NKCOL
#define KSPLIT 32
#define KCHUNK 128         // HH / KSPLIT
#define SCALE 0.08838834764831845f
#define TS 128             // attention tile (2 x 64-pos halves, online merge)
#define NSPLIT 33          // 33*128 = 4224 >= 4104
#define NEG_BIG 1e30f

// ---------------------------------------------------------------------------
// Kernel A/E: 32-row GEMM, K-split partials. 1 col/lane, coalesced W rows,
// wave-uniform x reads, next-quad W prefetch.
// ---------------------------------------------------------------------------
__global__ __launch_bounds__(256) void gemm32_part(
    const float* __restrict__ x, const float* __restrict__ W0,
    const float* __restrict__ W1, const float* __restrict__ W2,
    int n0, int n01, int ntot, float* __restrict__ part) {
  int nblk = ntot >> 8;
  int cb = blockIdx.x % nblk;
  int kb = blockIdx.x / nblk;
  int c = (cb << 8) + threadIdx.x;
  int k0 = kb << 7;   // KCHUNK = 128

  const float* W;
  int ldw, wc;
  if (c < n0)       { W = W0; ldw = n0;         wc = c; }
  else if (c < n01) { W = W1; ldw = n01 - n0;   wc = c - n0; }
  else              { W = W2; ldw = ntot - n01; wc = c - n01; }

  const float* wp = W + (size_t)k0 * ldw + wc;
  const float* xp = x + k0;

  float acc[ROWS];
#pragma unroll
  for (int r = 0; r < ROWS; ++r) acc[r] = 0.f;

  float w0 = wp[0], w1 = wp[ldw], w2 = wp[2 * ldw], w3 = wp[3 * ldw];
  for (int kk = 0; kk < KCHUNK; kk += 4) {
    int adv = (kk + 4 < KCHUNK) ? (ldw << 2) : 0;
    wp += adv;
    float n0r = wp[0], n1r = wp[ldw], n2r = wp[2 * ldw], n3r = wp[3 * ldw];
#pragma unroll
    for (int r = 0; r < ROWS; ++r) {
      const float4 xv = *(const float4*)(xp + (r << 12) + kk);
      acc[r] = fmaf(xv.x, w0, acc[r]);
      acc[r] = fmaf(xv.y, w1, acc[r]);
      acc[r] = fmaf(xv.z, w2, acc[r]);
      acc[r] = fmaf(xv.w, w3, acc[r]);
    }
    w0 = n0r; w1 = n1r; w2 = n2r; w3 = n3r;
  }
#pragma unroll
  for (int r = 0; r < ROWS; ++r) part[(size_t)((kb << 5) + r) * ntot + c] = acc[r];
}

// ---------------------------------------------------------------------------
// Kernel B: reduce K-split partials + RoPE + scatter k/v into caches;
// scaled q -> q_buf.
// ---------------------------------------------------------------------------
__global__ __launch_bounds__(256) void rope_reduce_scatter(
    const float* __restrict__ ypart, const float* __restrict__ cosb,
    const float* __restrict__ sinb, const int* __restrict__ cache_lens,
    float* __restrict__ q_buf, float* __restrict__ K_cache,
    float* __restrict__ V_cache) {
  int idx = blockIdx.x * 256 + threadIdx.x;
  if (idx < 81920) {                       // rope pairs: 32 rows * 2560 pairs
    int r = idx / 2560;
    int o = idx % 2560;
    int b = r >> 2, qp = r & 3;
    int c1, d;
    bool is_q;
    if (o < 2048) {                        // q pairs
      int h = o >> 6; d = o & 63;
      c1 = h * HD + d;
      is_q = true;
    } else {                               // k pairs
      int ok = o - 2048;
      int kvh = ok >> 6; d = ok & 63;
      c1 = NQCOL + kvh * HD + d;
      is_q = false;
    }
    int c2 = c1 + 64;
    float s1 = 0.f, s2 = 0.f;
#pragma unroll
    for (int kb = 0; kb < KSPLIT; ++kb) {
      s1 += ypart[(size_t)((kb << 5) + r) * NTOTC + c1];
      s2 += ypart[(size_t)((kb << 5) + r) * NTOTC + c2];
    }
    float cv = cosb[(r << 7) + d];
    float sv = sinb[(r << 7) + d];
    float o1 = s1 * cv - s2 * sv;
    float o2 = s2 * cv + s1 * sv;
    if (is_q) {
      q_buf[(size_t)r * NQCOL + c1] = o1 * SCALE;
      q_buf[(size_t)r * NQCOL + c2] = o2 * SCALE;
    } else {
      int kvh = (c1 - NQCOL) >> 7;
      int pos = cache_lens[b] + qp;
      size_t base = ((size_t)(b * CAP + pos) * NKV + kvh) * HD;
      K_cache[base + d] = o1;
      K_cache[base + d + 64] = o2;
    }
  } else {                                 // v singles: 32 rows * 1024 cols
    int vi = idx - 81920;
    int r = vi >> 10;
    int cc = vi & 1023;
    int b = r >> 2, qp = r & 3;
    int c = NQCOL + NKCOL + cc;
    float s = 0.f;
#pragma unroll
    for (int kb = 0; kb < KSPLIT; ++kb)
      s += ypart[(size_t)((kb << 5) + r) * NTOTC + c];
    int kvh = cc >> 7, dd = cc & 127;
    int pos = cache_lens[b] + qp;
    V_cache[((size_t)(b * CAP + pos) * NKV + kvh) * HD + dd] = s;
  }
}

// ---------------------------------------------------------------------------
// Kernel C: attention partials. 1 block = one (b,kv) x one 128-pos tile
// processed as two 64-pos halves with online-softmax merge.
// Per half:
//   Stage: 64 K rows -> LDS (coalesced 512B rows, XOR swizzle (r&7)<<4).
//   QK: wave w owns q's [4w,4w+4) (all have qp == w); lane: pg=l>>2 (pos
//       pg+16i), dq=l&3 (dim quarter). acc[4pos][4q] over 32 dims;
//       butterfly over dq -> full dots; mask; per-q max/sum via shfl.
//   Merge: nm = max(m_old, m_half); e = exp(s-nm); l = l_old*alpha + sum e;
//       alpha = exp(m_old-nm) -> alpha_lds; p (pre-scaled) -> p_lds.
//   PV: wave w owns pos [16w,16w+16); lane: dg=l&31 (4 dims), qh=l>>5 (8 q).
//       o_run = o_run*alpha[q] + sum p*v; V direct from global (coalesced).
// Final: 4 wave partials merged via LDS (k_lds reuse) -> part_o/m/l.
// ---------------------------------------------------------------------------
__global__ __launch_bounds__(256) void attn_partial(
    const float* __restrict__ q_buf, const float* __restrict__ K_cache,
    const float* __restrict__ V_cache, const int* __restrict__ cache_lens,
    float* __restrict__ part_o, float* __restrict__ part_m,
    float* __restrict__ part_l) {
  __shared__ __align__(16) float k_lds[64 * 128];   // swizzled; reused as o_merge
  __shared__ __align__(16) float q_lds[16 * 132];
  __shared__ __align__(16) float p_lds[64 * 20];    // [pos][q], stride 20
  __shared__ float ml_lds[32];                      // m_run[16], l_run[16]
  __shared__ float alpha_lds[16];

  int g = blockIdx.x & 63;
  int split = blockIdx.x >> 6;
  int b = g >> 3, kv = g & 7;
  int t = threadIdx.x, w = t >> 6, lane = t & 63;
  int cl = cache_lens[b];
  int cl3 = cl + 3;
  int jb = split * TS;

  // stage q (padded rows)
  for (int i = t; i < 512; i += 256) {
    int qi = i >> 5, d4 = (i & 31) << 2;
    const float4 v = *(const float4*)(q_buf +
        (size_t)((b << 2) + (qi >> 2)) * NQCOL + (((kv << 2) + (qi & 3)) << 7) + d4);
    *(float4*)&q_lds[qi * 132 + d4] = v;
  }
  if (t < 16) { ml_lds[t] = -NEG_BIG; ml_lds[16 + t] = 0.f; }

  int pg = lane >> 2, dq = lane & 3;
  int dg = lane & 31, qh = lane >> 5;

  float orun[4][8];
#pragma unroll
  for (int di = 0; di < 4; ++di)
#pragma unroll
    for (int qq = 0; qq < 8; ++qq) orun[di][qq] = 0.f;

  for (int h = 0; h < 2; ++h) {
    int jbh = jb + (h << 6);

    // stage K half-tile: coalesced rows -> swizzled LDS
    for (int i = t; i < 2048; i += 256) {
      int r = i >> 5;
      int cbyte = (i & 31) << 4;
      int j = min(jbh + r, cl3);
      const float4 vv = *(const float4*)((const char*)K_cache +
          (((size_t)(b * CAP + j) * NKV + kv) << 9) + cbyte);
      *(float4*)((char*)k_lds + ((size_t)r << 9) + (cbyte ^ ((r & 7) << 4))) = vv;
    }
    __syncthreads();   // stage visible; also fences prior-half p_lds reads

    // ---- QK ----
    float acc[4][4];
#pragma unroll
    for (int i = 0; i < 4; ++i)
#pragma unroll
      for (int j = 0; j < 4; ++j) acc[i][j] = 0.f;

    for (int s = 0; s < 8; ++s) {
      int d0 = (dq << 5) + (s << 2);
      const float4 q0 = *(const float4*)&q_lds[(4 * w + 0) * 132 + d0];
      const float4 q1 = *(const float4*)&q_lds[(4 * w + 1) * 132 + d0];
      const float4 q2 = *(const float4*)&q_lds[(4 * w + 2) * 132 + d0];
      const float4 q3 = *(const float4*)&q_lds[(4 * w + 3) * 132 + d0];
#pragma unroll
      for (int i = 0; i < 4; ++i) {
        int r = pg + (i << 4);
        const float4 kk = *(const float4*)((const char*)k_lds +
            (r << 9) + ((unsigned)(d0 << 2) ^ ((r & 7) << 4)));
        acc[i][0] = fmaf(kk.x, q0.x, acc[i][0]);
        acc[i][0] = fmaf(kk.y, q0.y, acc[i][0]);
        acc[i][0] = fmaf(kk.z, q0.z, acc[i][0]);
        acc[i][0] = fmaf(kk.w, q0.w, acc[i][0]);
        acc[i][1] = fmaf(kk.x, q1.x, acc[i][1]);
        acc[i][1] = fmaf(kk.y, q1.y, acc[i][1]);
        acc[i][1] = fmaf(kk.z, q1.z, acc[i][1]);
        acc[i][1] = fmaf(kk.w, q1.w, acc[i][1]);
        acc[i][2] = fmaf(kk.x, q2.x, acc[i][2]);
        acc[i][2] = fmaf(kk.y, q2.y, acc[i][2]);
        acc[i][2] = fmaf(kk.z, q2.z, acc[i][2]);
        acc[i][2] = fmaf(kk.w, q2.w, acc[i][2]);
        acc[i][3] = fmaf(kk.x, q3.x, acc[i][3]);
        acc[i][3] = fmaf(kk.y, q3.y, acc[i][3]);
        acc[i][3] = fmaf(kk.z, q3.z, acc[i][3]);
        acc[i][3] = fmaf(kk.w, q3.w, acc[i][3]);
      }
    }

    // butterfly-reduce over dq (lane bits 0-1): full dot products
#pragma unroll
    for (int i = 0; i < 4; ++i)
#pragma unroll
      for (int j = 0; j < 4; ++j) {
        float v = acc[i][j];
        v += __shfl_xor(v, 1);
        v += __shfl_xor(v, 2);
        acc[i][j] = v;
      }

    // mask (all q's of wave w have row offset qp == w)
    bool okv[4];
#pragma unroll
    for (int i = 0; i < 4; ++i) {
      okv[i] = (jbh + pg + (i << 4)) <= (cl + w);
#pragma unroll
      for (int j = 0; j < 4; ++j)
        if (!okv[i]) acc[i][j] = -NEG_BIG;
    }

    // per-q softmax + online merge with running (m,l)
    float m4[4], l4[4], a4[4];
#pragma unroll
    for (int j = 0; j < 4; ++j) {
      float m = fmaxf(fmaxf(acc[0][j], acc[1][j]), fmaxf(acc[2][j], acc[3][j]));
      m = fmaxf(m, __shfl_xor(m, 4));
      m = fmaxf(m, __shfl_xor(m, 8));
      m = fmaxf(m, __shfl_xor(m, 16));
      m = fmaxf(m, __shfl_xor(m, 32));
      float mo = ml_lds[(w << 2) + j];
      float lo = ml_lds[16 + (w << 2) + j];
      float nm = fmaxf(mo, m);
      float l = 0.f;
#pragma unroll
      for (int i = 0; i < 4; ++i) {
        float e = okv[i] ? __expf(acc[i][j] - nm) : 0.f;
        acc[i][j] = e;
        l += e;
      }
      l += __shfl_xor(l, 4);
      l += __shfl_xor(l, 8);
      l += __shfl_xor(l, 16);
      l += __shfl_xor(l, 32);
      float al = __expf(mo - nm);
      m4[j] = nm; l4[j] = lo * al + l; a4[j] = al;
    }

    // p -> LDS (pre-scaled to new max); m/l/alpha -> LDS
#pragma unroll
    for (int i = 0; i < 4; ++i) {
      float pv = (dq == 0) ? acc[i][0] : (dq == 1) ? acc[i][1]
               : (dq == 2) ? acc[i][2] : acc[i][3];
      p_lds[(pg + (i << 4)) * 20 + (w << 2) + dq] = pv;
    }
    if (lane < 4) {
      float mm = (lane == 0) ? m4[0] : (lane == 1) ? m4[1] : (lane == 2) ? m4[2] : m4[3];
      float ll = (lane == 0) ? l4[0] : (lane == 1) ? l4[1] : (lane == 2) ? l4[2] : l4[3];
      float aa = (lane == 0) ? a4[0] : (lane == 1) ? a4[1] : (lane == 2) ? a4[2] : a4[3];
      ml_lds[(w << 2) + lane] = mm;
      ml_lds[16 + (w << 2) + lane] = ll;
      alpha_lds[(w << 2) + lane] = aa;
    }
    __syncthreads();

    // ---- PV ---- rescale old accumulators, then accumulate this half
    float alq[8];
#pragma unroll
    for (int qq = 0; qq < 8; ++qq) alq[qq] = alpha_lds[(qh << 3) + qq];
#pragma unroll
    for (int di = 0; di < 4; ++di)
#pragma unroll
      for (int qq = 0; qq < 8; ++qq) orun[di][qq] *= alq[qq];

    for (int jj = 0; jj < 16; ++jj) {
      int j = (w << 4) + jj;
      int jg = min(jbh + j, cl3);
      const float4 vv = *(const float4*)(V_cache +
          (((size_t)(b * CAP + jg) * NKV + kv) << 7) + (dg << 2));
      const float4 pa = *(const float4*)&p_lds[j * 20 + (qh << 3)];
      const float4 pb = *(const float4*)&p_lds[j * 20 + (qh << 3) + 4];
      orun[0][0] = fmaf(vv.x, pa.x, orun[0][0]); orun[1][0] = fmaf(vv.y, pa.x, orun[1][0]);
      orun[2][0] = fmaf(vv.z, pa.x, orun[2][0]); orun[3][0] = fmaf(vv.w, pa.x, orun[3][0]);
      orun[0][1] = fmaf(vv.x, pa.y, orun[0][1]); orun[1][1] = fmaf(vv.y, pa.y, orun[1][1]);
      orun[2][1] = fmaf(vv.z, pa.y, orun[2][1]); orun[3][1] = fmaf(vv.w, pa.y, orun[3][1]);
      orun[0][2] = fmaf(vv.x, pa.z, orun[0][2]); orun[1][2] = fmaf(vv.y, pa.z, orun[1][2]);
      orun[2][2] = fmaf(vv.z, pa.z, orun[2][2]); orun[3][2] = fmaf(vv.w, pa.z, orun[3][2]);
      orun[0][3] = fmaf(vv.x, pa.w, orun[0][3]); orun[1][3] = fmaf(vv.y, pa.w, orun[1][3]);
      orun[2][3] = fmaf(vv.z, pa.w, orun[2][3]); orun[3][3] = fmaf(vv.w, pa.w, orun[3][3]);
      orun[0][4] = fmaf(vv.x, pb.x, orun[0][4]); orun[1][4] = fmaf(vv.y, pb.x, orun[1][4]);
      orun[2][4] = fmaf(vv.z, pb.x, orun[2][4]); orun[3][4] = fmaf(vv.w, pb.x, orun[3][4]);
      orun[0][5] = fmaf(vv.x, pb.y, orun[0][5]); orun[1][5] = fmaf(vv.y, pb.y, orun[1][5]);
      orun[2][5] = fmaf(vv.z, pb.y, orun[2][5]); orun[3][5] = fmaf(vv.w, pb.y, orun[3][5]);
      orun[0][6] = fmaf(vv.x, pb.z, orun[0][6]); orun[1][6] = fmaf(vv.y, pb.z, orun[1][6]);
      orun[2][6] = fmaf(vv.z, pb.z, orun[2][6]); orun[3][6] = fmaf(vv.w, pb.z, orun[3][6]);
      orun[0][7] = fmaf(vv.x, pb.w, orun[0][7]); orun[1][7] = fmaf(vv.y, pb.w, orun[1][7]);
      orun[2][7] = fmaf(vv.z, pb.w, orun[2][7]); orun[3][7] = fmaf(vv.w, pb.w, orun[3][7]);
    }
  }

  // wave-partial o -> LDS (reuse k_lds as o_merge[w][16][128])
  float* om = k_lds;
#pragma unroll
  for (int qq = 0; qq < 8; ++qq) {
    int q = (qh << 3) + qq;
    float4 ov = make_float4(orun[0][qq], orun[1][qq], orun[2][qq], orun[3][qq]);
    *(float4*)&om[(size_t)(((w << 4) + q) << 7) + (dg << 2)] = ov;
  }
  __syncthreads();

  // merge 4 wave-partials -> global split partial
  size_t ob = (size_t)(split * 64 + g) * 2048;
  for (int i = t; i < 2048; i += 256)
    part_o[ob + i] = om[i] + om[i + 2048] + om[i + 4096] + om[i + 6144];
  if (t < 16) {
    part_m[(size_t)(split * 64 + g) * 16 + t] = ml_lds[t];
    part_l[(size_t)(split * 64 + g) * 16 + t] = ml_lds[16 + t];
  }
}

// ---------------------------------------------------------------------------
// Kernel D: combine seq-split partials -> attn_out (32 x 4096, head-major)
// ---------------------------------------------------------------------------
__global__ __launch_bounds__(256) void attn_combine(
    const float* __restrict__ part_o, const float* __restrict__ part_m,
    const float* __restrict__ part_l, float* __restrict__ attn_out) {
  int idx = blockIdx.x * 256 + threadIdx.x;  // 131072
  int d = idx & 127;
  int qi = (idx >> 7) & 15;
  int g = idx >> 11;
  int b = g >> 3, kv = g & 7;
  float M = -NEG_BIG;
#pragma unroll 4
  for (int s = 0; s < NSPLIT; ++s) M = fmaxf(M, part_m[(size_t)(s * 64 + g) * 16 + qi]);
  float osum = 0.f, L = 0.f;
#pragma unroll 4
  for (int s = 0; s < NSPLIT; ++s) {
    size_t ml = (size_t)(s * 64 + g) * 16 + qi;
    float wgt = __expf(part_m[ml] - M);
    osum += part_o[ml * 128 + d] * wgt;
    L += part_l[ml] * wgt;
  }
  int qp = qi >> 2, gi = qi & 3;
  attn_out[(size_t)((b << 2) + qp) * NQCOL + (((kv << 2) + gi) << 7) + d] = osum / L;
}

// ---------------------------------------------------------------------------
// Kernel F: reduce O-proj partials -> d_out
// ---------------------------------------------------------------------------
__global__ __launch_bounds__(256) void reduce_out(
    const float* __restrict__ opart, float* __restrict__ out) {
  int idx = blockIdx.x * 256 + threadIdx.x;  // 131072
  int c = idx & 4095;
  int r = idx >> 12;
  float s = 0.f;
#pragma unroll
  for (int kb = 0; kb < KSPLIT; ++kb)
    s += opart[(size_t)((kb << 5) + r) * NQCOL + c];
  out[idx] = s;
}

extern "C" void kernel_launch(void* const* d_in, const int* in_sizes, int n_in,
                              void* d_out, int out_size, void* d_ws, size_t ws_size,
                              hipStream_t stream) {
  const float* hidden = (const float*)d_in[0];
  const float* cosb   = (const float*)d_in[1];
  const float* sinb   = (const float*)d_in[2];
  const float* Wq     = (const float*)d_in[3];
  const float* Wk     = (const float*)d_in[4];
  const float* Wv     = (const float*)d_in[5];
  const float* Wo     = (const float*)d_in[6];
  float* K_cache      = (float*)d_in[7];
  float* V_cache      = (float*)d_in[8];
  const int* cache_lens = (const int*)d_in[9];
  float* out = (float*)d_out;

  // buf0 (aliased): ypart (32*32*6144 = 6.29M f, the max) -> part_o
  // (33*64*2048 = 4.33M f) -> opart (32*32*4096 = 4.19M f).  Total ws 26.5MB.
  const size_t BUF0 = (size_t)KSPLIT * ROWS * NTOTC;  // 6291456 floats
  float* buf0     = (float*)d_ws;
  float* q_buf    = buf0 + BUF0;                      // 131072
  float* part_m   = q_buf + (size_t)ROWS * NQCOL;     // 33*64*16
  float* part_l   = part_m + (size_t)NSPLIT * 64 * 16;
  float* attn_out = part_l + (size_t)NSPLIT * 64 * 16;  // 131072

  // A: QKV projection partials
  gemm32_part<<<(NTOTC / 256) * KSPLIT, 256, 0, stream>>>(
      hidden, Wq, Wk, Wv, NQCOL, NQCOL + NKCOL, NTOTC, buf0);
  // B: reduce + RoPE + scatter
  rope_reduce_scatter<<<448, 256, 0, stream>>>(
      buf0, cosb, sinb, cache_lens, q_buf, K_cache, V_cache);
  // C: attention partials (33 splits x 64 groups)
  attn_partial<<<64 * NSPLIT, 256, 0, stream>>>(
      q_buf, K_cache, V_cache, cache_lens, buf0, part_m, part_l);
  // D: combine
  attn_combine<<<512, 256, 0, stream>>>(buf0, part_m, part_l, attn_out);
  // E: O projection partials
  gemm32_part<<<(NQCOL / 256) * KSPLIT, 256, 0, stream>>>(
      attn_out, Wo, Wo, Wo, NQCOL, NQCOL, NQCOL, buf0);
  // F: reduce to output
  reduce_out<<<512, 256, 0, stream>>>(buf0, out);
}

// Round 7
// 490.940 us; speedup vs baseline: 1.4411x; 1.1334x over previous
//
#include <hip/hip_runtime.h>
#include <hip/hip_bf16.h>

// Problem constants
#define BB 8
#define QQ 4
#define HH 4096
#define NH 32
#define NKV 8
#define HD 128
#define CAP 4100
#define ROWS 32            // B*Q
#define NQCOL 4096         // NH*HD
#define NKCOL 1024         // NKV*HD
#define NTOTC 6144         // NQCOL + 2*NKCOL
#define KSPLIT 32
#define KCHUNK 128         // HH / KSPLIT
#define SCALE 0.08838834764831845f
#define TS 128             // attention tile (4 x 32-pos sub-tiles, online merge)
#define NSPLIT 33          // 33*128 = 4224 >= 4104
#define NEG_BIG 1e30f

// ---------------------------------------------------------------------------
// Kernel A/E: 32-row GEMM, K-split partials. x chunk staged in LDS (broadcast
// ds reads), W streamed with 2-deep prefetch + nontemporal loads.
// WIDE: 512 cols/block, 2 cols/thread (float2 W); else 256 cols, 1 col.
// ---------------------------------------------------------------------------
template <bool WIDE>
__global__ __launch_bounds__(256) void gemm32_part(
    const float* __restrict__ x, const float* __restrict__ W0,
    const float* __restrict__ W1, const float* __restrict__ W2,
    int n0, int n01, int ntot, float* __restrict__ part) {
  __shared__ __align__(16) float x_lds[ROWS * KCHUNK];   // 16 KB
  const int CPB = WIDE ? 512 : 256;
  int nblk = ntot / CPB;
  int cb = blockIdx.x % nblk;
  int kb = blockIdx.x / nblk;
  int k0 = kb << 7;

  // stage x chunk (32 rows x 128 k) — both A and E inputs have row stride 4096
  for (int i = threadIdx.x; i < 1024; i += 256) {
    int r = i >> 5, gq = (i & 31) << 2;
    *(float4*)&x_lds[(r << 7) + gq] =
        *(const float4*)(x + ((size_t)r << 12) + k0 + gq);
  }
  __syncthreads();

  int c = cb * CPB + (WIDE ? (threadIdx.x << 1) : (int)threadIdx.x);
  const float* W; int ldw, wc;
  if (c < n0)       { W = W0; ldw = n0;         wc = c; }
  else if (c < n01) { W = W1; ldw = n01 - n0;   wc = c - n0; }
  else              { W = W2; ldw = ntot - n01; wc = c - n01; }
  const float* wp = W + (size_t)k0 * ldw + wc;

  if (WIDE) {
    float acc[ROWS][2];
#pragma unroll
    for (int r = 0; r < ROWS; ++r) { acc[r][0] = 0.f; acc[r][1] = 0.f; }
    float2 a[4], bq[4];
#pragma unroll
    for (int u = 0; u < 4; ++u) {
      const float* p0 = wp + (size_t)u * ldw;
      const float* p1 = wp + (size_t)(u + 4) * ldw;
      a[u].x = __builtin_nontemporal_load(p0);
      a[u].y = __builtin_nontemporal_load(p0 + 1);
      bq[u].x = __builtin_nontemporal_load(p1);
      bq[u].y = __builtin_nontemporal_load(p1 + 1);
    }
    for (int kk = 0; kk < KCHUNK; kk += 4) {
      float2 cq[4];
      if (kk + 8 < KCHUNK) {
#pragma unroll
        for (int u = 0; u < 4; ++u) {
          const float* p = wp + (size_t)(kk + 8 + u) * ldw;
          cq[u].x = __builtin_nontemporal_load(p);
          cq[u].y = __builtin_nontemporal_load(p + 1);
        }
      } else {
#pragma unroll
        for (int u = 0; u < 4; ++u) cq[u] = a[u];
      }
#pragma unroll
      for (int r = 0; r < ROWS; ++r) {
        const float4 xv = *(const float4*)&x_lds[(r << 7) + kk];
        acc[r][0] = fmaf(xv.x, a[0].x, acc[r][0]);
        acc[r][1] = fmaf(xv.x, a[0].y, acc[r][1]);
        acc[r][0] = fmaf(xv.y, a[1].x, acc[r][0]);
        acc[r][1] = fmaf(xv.y, a[1].y, acc[r][1]);
        acc[r][0] = fmaf(xv.z, a[2].x, acc[r][0]);
        acc[r][1] = fmaf(xv.z, a[2].y, acc[r][1]);
        acc[r][0] = fmaf(xv.w, a[3].x, acc[r][0]);
        acc[r][1] = fmaf(xv.w, a[3].y, acc[r][1]);
      }
#pragma unroll
      for (int u = 0; u < 4; ++u) { a[u] = bq[u]; bq[u] = cq[u]; }
    }
#pragma unroll
    for (int r = 0; r < ROWS; ++r) {
      float2 st = make_float2(acc[r][0], acc[r][1]);
      *(float2*)(part + (size_t)((kb << 5) + r) * ntot + c) = st;
    }
  } else {
    float acc[ROWS];
#pragma unroll
    for (int r = 0; r < ROWS; ++r) acc[r] = 0.f;
    float a[4], bq[4];
#pragma unroll
    for (int u = 0; u < 4; ++u) {
      a[u] = __builtin_nontemporal_load(wp + (size_t)u * ldw);
      bq[u] = __builtin_nontemporal_load(wp + (size_t)(u + 4) * ldw);
    }
    for (int kk = 0; kk < KCHUNK; kk += 4) {
      float cq[4];
      if (kk + 8 < KCHUNK) {
#pragma unroll
        for (int u = 0; u < 4; ++u)
          cq[u] = __builtin_nontemporal_load(wp + (size_t)(kk + 8 + u) * ldw);
      } else {
#pragma unroll
        for (int u = 0; u < 4; ++u) cq[u] = a[u];
      }
#pragma unroll
      for (int r = 0; r < ROWS; ++r) {
        const float4 xv = *(const float4*)&x_lds[(r << 7) + kk];
        acc[r] = fmaf(xv.x, a[0], acc[r]);
        acc[r] = fmaf(xv.y, a[1], acc[r]);
        acc[r] = fmaf(xv.z, a[2], acc[r]);
        acc[r] = fmaf(xv.w, a[3], acc[r]);
      }
#pragma unroll
      for (int u = 0; u < 4; ++u) { a[u] = bq[u]; bq[u] = cq[u]; }
    }
#pragma unroll
    for (int r = 0; r < ROWS; ++r)
      part[(size_t)((kb << 5) + r) * ntot + c] = acc[r];
  }
}

// ---------------------------------------------------------------------------
// Kernel B: reduce K-split partials + RoPE + scatter k/v into caches;
// scaled q -> q_buf.
// ---------------------------------------------------------------------------
__global__ __launch_bounds__(256) void rope_reduce_scatter(
    const float* __restrict__ ypart, const float* __restrict__ cosb,
    const float* __restrict__ sinb, const int* __restrict__ cache_lens,
    float* __restrict__ q_buf, float* __restrict__ K_cache,
    float* __restrict__ V_cache) {
  int idx = blockIdx.x * 256 + threadIdx.x;
  if (idx < 81920) {                       // rope pairs: 32 rows * 2560 pairs
    int r = idx / 2560;
    int o = idx % 2560;
    int b = r >> 2, qp = r & 3;
    int c1, d;
    bool is_q;
    if (o < 2048) {                        // q pairs
      int h = o >> 6; d = o & 63;
      c1 = h * HD + d;
      is_q = true;
    } else {                               // k pairs
      int ok = o - 2048;
      int kvh = ok >> 6; d = ok & 63;
      c1 = NQCOL + kvh * HD + d;
      is_q = false;
    }
    int c2 = c1 + 64;
    float s1 = 0.f, s2 = 0.f;
#pragma unroll
    for (int kb = 0; kb < KSPLIT; ++kb) {
      s1 += ypart[(size_t)((kb << 5) + r) * NTOTC + c1];
      s2 += ypart[(size_t)((kb << 5) + r) * NTOTC + c2];
    }
    float cv = cosb[(r << 7) + d];
    float sv = sinb[(r << 7) + d];
    float o1 = s1 * cv - s2 * sv;
    float o2 = s2 * cv + s1 * sv;
    if (is_q) {
      q_buf[(size_t)r * NQCOL + c1] = o1 * SCALE;
      q_buf[(size_t)r * NQCOL + c2] = o2 * SCALE;
    } else {
      int kvh = (c1 - NQCOL) >> 7;
      int pos = cache_lens[b] + qp;
      size_t base = ((size_t)(b * CAP + pos) * NKV + kvh) * HD;
      K_cache[base + d] = o1;
      K_cache[base + d + 64] = o2;
    }
  } else {                                 // v singles: 32 rows * 1024 cols
    int vi = idx - 81920;
    int r = vi >> 10;
    int cc = vi & 1023;
    int b = r >> 2, qp = r & 3;
    int c = NQCOL + NKCOL + cc;
    float s = 0.f;
#pragma unroll
    for (int kb = 0; kb < KSPLIT; ++kb)
      s += ypart[(size_t)((kb << 5) + r) * NTOTC + c];
    int kvh = cc >> 7, dd = cc & 127;
    int pos = cache_lens[b] + qp;
    V_cache[((size_t)(b * CAP + pos) * NKV + kvh) * HD + dd] = s;
  }
}

// ---------------------------------------------------------------------------
// Kernel C: attention partials. 1 block = (b,kv) x 128-pos tile, processed
// as four 32-row sub-tiles with online softmax.
//  - K sub-tiles double-buffered in LDS: next sub-tile global loads issue
//    before QK(cur); ds_write after QK; one barrier makes them visible.
//  - V rows prefetched to registers at sub-tile start, consumed in PV.
//  - q_lds quarter-padded (dq*36 floats) -> conflict-free q broadcasts.
//  - K rows XOR-swizzled ((r&7)<<4) -> minimal-conflict ds_read_b128.
// QK: wave w owns q [4w,4w+4); lane: pg=l>>2 (pos pg,pg+16), dq=l&3 (dim
//     quarter). acc[2][4]; butterfly over dq; per-q shfl max/sum.
// PV: wave w owns pos [8w,8w+8); lane: dg=l&31 (4 dims), qh=l>>5 (8 q's).
// ---------------------------------------------------------------------------
__global__ __launch_bounds__(256) void attn_partial(
    const float* __restrict__ q_buf, const float* __restrict__ K_cache,
    const float* __restrict__ V_cache, const int* __restrict__ cache_lens,
    float* __restrict__ part_o, float* __restrict__ part_m,
    float* __restrict__ part_l) {
  __shared__ __align__(16) float k_lds[2][32 * 128];  // 32 KB; reused as o_merge
  __shared__ __align__(16) float q_lds[16 * 144];     // quarter-padded
  __shared__ __align__(16) float p_lds[32 * 20];      // [pos][q], stride 20
  __shared__ float ml_lds[32];                        // m_run[16], l_run[16]
  __shared__ float alpha_lds[16];

  int g = blockIdx.x & 63;
  int split = blockIdx.x >> 6;
  int b = g >> 3, kv = g & 7;
  int t = threadIdx.x, w = t >> 6, lane = t & 63;
  int cl = cache_lens[b];
  int cl3 = cl + 3;
  int jb = split * TS;

  // stage q: [qi][dq quarter (36-stride)][8 granules]
  for (int i = t; i < 512; i += 256) {
    int qi = i >> 5, d4 = (i & 31) << 2;
    const float4 v = *(const float4*)(q_buf +
        (size_t)((b << 2) + (qi >> 2)) * NQCOL + (((kv << 2) + (qi & 3)) << 7) + d4);
    *(float4*)&q_lds[qi * 144 + (d4 >> 5) * 36 + (d4 & 31)] = v;
  }
  if (t < 16) { ml_lds[t] = -NEG_BIG; ml_lds[16 + t] = 0.f; }

  int pg = lane >> 2, dq = lane & 3;
  int dg = lane & 31, qh = lane >> 5;

  // prologue: stage sub-tile 0 into k_lds[0]
  float4 kreg[4];
#pragma unroll
  for (int u = 0; u < 4; ++u) {
    int i = t + (u << 8);
    int r = i >> 5, gk = i & 31;
    int j = min(jb + r, cl3);
    kreg[u] = *(const float4*)((const char*)K_cache +
        (((size_t)(b * CAP + j) * NKV + kv) << 9) + (gk << 4));
  }
#pragma unroll
  for (int u = 0; u < 4; ++u) {
    int i = t + (u << 8);
    int r = i >> 5, gk = i & 31;
    *(float4*)((char*)&k_lds[0][0] + (r << 9) + ((gk << 4) ^ ((r & 7) << 4))) = kreg[u];
  }
  __syncthreads();

  float orun[4][8];
#pragma unroll
  for (int di = 0; di < 4; ++di)
#pragma unroll
    for (int qq = 0; qq < 8; ++qq) orun[di][qq] = 0.f;

  int cur = 0;
  for (int st = 0; st < 4; ++st) {
    int jbh = jb + (st << 5);

    // V prefetch (consumed in PV after the barrier — latency hides under QK)
    float4 vreg[8];
#pragma unroll
    for (int jj = 0; jj < 8; ++jj) {
      int j = min(jbh + (w << 3) + jj, cl3);
      vreg[jj] = *(const float4*)(V_cache +
          (((size_t)(b * CAP + j) * NKV + kv) << 7) + (dg << 2));
    }
    // K prefetch for next sub-tile (ds_write deferred until after QK)
    bool have_next = (st < 3);
    if (have_next) {
      int jbn = jbh + 32;
#pragma unroll
      for (int u = 0; u < 4; ++u) {
        int i = t + (u << 8);
        int r = i >> 5, gk = i & 31;
        int j = min(jbn + r, cl3);
        kreg[u] = *(const float4*)((const char*)K_cache +
            (((size_t)(b * CAP + j) * NKV + kv) << 9) + (gk << 4));
      }
    }

    // ---- QK on k_lds[cur] ----
    const float* kl = &k_lds[cur][0];
    float acc[2][4];
#pragma unroll
    for (int i = 0; i < 2; ++i)
#pragma unroll
      for (int j = 0; j < 4; ++j) acc[i][j] = 0.f;

    for (int s = 0; s < 8; ++s) {
      int qoff = dq * 36 + (s << 2);
      const float4 q0 = *(const float4*)&q_lds[(4 * w + 0) * 144 + qoff];
      const float4 q1 = *(const float4*)&q_lds[(4 * w + 1) * 144 + qoff];
      const float4 q2 = *(const float4*)&q_lds[(4 * w + 2) * 144 + qoff];
      const float4 q3 = *(const float4*)&q_lds[(4 * w + 3) * 144 + qoff];
#pragma unroll
      for (int i = 0; i < 2; ++i) {
        int r = pg + (i << 4);
        const float4 kk = *(const float4*)((const char*)kl +
            (r << 9) + ((unsigned)((dq << 7) | (s << 4)) ^ ((r & 7) << 4)));
        acc[i][0] = fmaf(kk.x, q0.x, acc[i][0]);
        acc[i][0] = fmaf(kk.y, q0.y, acc[i][0]);
        acc[i][0] = fmaf(kk.z, q0.z, acc[i][0]);
        acc[i][0] = fmaf(kk.w, q0.w, acc[i][0]);
        acc[i][1] = fmaf(kk.x, q1.x, acc[i][1]);
        acc[i][1] = fmaf(kk.y, q1.y, acc[i][1]);
        acc[i][1] = fmaf(kk.z, q1.z, acc[i][1]);
        acc[i][1] = fmaf(kk.w, q1.w, acc[i][1]);
        acc[i][2] = fmaf(kk.x, q2.x, acc[i][2]);
        acc[i][2] = fmaf(kk.y, q2.y, acc[i][2]);
        acc[i][2] = fmaf(kk.z, q2.z, acc[i][2]);
        acc[i][2] = fmaf(kk.w, q2.w, acc[i][2]);
        acc[i][3] = fmaf(kk.x, q3.x, acc[i][3]);
        acc[i][3] = fmaf(kk.y, q3.y, acc[i][3]);
        acc[i][3] = fmaf(kk.z, q3.z, acc[i][3]);
        acc[i][3] = fmaf(kk.w, q3.w, acc[i][3]);
      }
    }

    // butterfly over dq lanes -> full dots
#pragma unroll
    for (int i = 0; i < 2; ++i)
#pragma unroll
      for (int j = 0; j < 4; ++j) {
        float v = acc[i][j];
        v += __shfl_xor(v, 1);
        v += __shfl_xor(v, 2);
        acc[i][j] = v;
      }

    // mask
    bool okv[2];
#pragma unroll
    for (int i = 0; i < 2; ++i) {
      okv[i] = (jbh + pg + (i << 4)) <= (cl + w);
#pragma unroll
      for (int j = 0; j < 4; ++j)
        if (!okv[i]) acc[i][j] = -NEG_BIG;
    }

    // per-q online softmax merge
    float m4[4], l4[4], a4[4];
#pragma unroll
    for (int j = 0; j < 4; ++j) {
      float m = fmaxf(acc[0][j], acc[1][j]);
      m = fmaxf(m, __shfl_xor(m, 4));
      m = fmaxf(m, __shfl_xor(m, 8));
      m = fmaxf(m, __shfl_xor(m, 16));
      m = fmaxf(m, __shfl_xor(m, 32));
      float mo = ml_lds[(w << 2) + j];
      float lo = ml_lds[16 + (w << 2) + j];
      float nm = fmaxf(mo, m);
      float l = 0.f;
#pragma unroll
      for (int i = 0; i < 2; ++i) {
        float e = okv[i] ? __expf(acc[i][j] - nm) : 0.f;
        acc[i][j] = e;
        l += e;
      }
      l += __shfl_xor(l, 4);
      l += __shfl_xor(l, 8);
      l += __shfl_xor(l, 16);
      l += __shfl_xor(l, 32);
      float al = __expf(mo - nm);
      m4[j] = nm; l4[j] = lo * al + l; a4[j] = al;
    }

    // p -> LDS; m/l/alpha -> LDS
#pragma unroll
    for (int i = 0; i < 2; ++i) {
      float pv = (dq == 0) ? acc[i][0] : (dq == 1) ? acc[i][1]
               : (dq == 2) ? acc[i][2] : acc[i][3];
      p_lds[(pg + (i << 4)) * 20 + (w << 2) + dq] = pv;
    }
    if (lane < 4) {
      float mm = (lane == 0) ? m4[0] : (lane == 1) ? m4[1] : (lane == 2) ? m4[2] : m4[3];
      float ll = (lane == 0) ? l4[0] : (lane == 1) ? l4[1] : (lane == 2) ? l4[2] : l4[3];
      float aa = (lane == 0) ? a4[0] : (lane == 1) ? a4[1] : (lane == 2) ? a4[2] : a4[3];
      ml_lds[(w << 2) + lane] = mm;
      ml_lds[16 + (w << 2) + lane] = ll;
      alpha_lds[(w << 2) + lane] = aa;
    }
    // ds_write staged K (next sub-tile) into the other buffer
    if (have_next) {
      char* dst = (char*)&k_lds[cur ^ 1][0];
#pragma unroll
      for (int u = 0; u < 4; ++u) {
        int i = t + (u << 8);
        int r = i >> 5, gk = i & 31;
        *(float4*)(dst + (r << 9) + ((gk << 4) ^ ((r & 7) << 4))) = kreg[u];
      }
    }
    __syncthreads();   // p/alpha visible; next K buffer visible

    // ---- PV ---- (V from registers)
    float alq[8];
#pragma unroll
    for (int qq = 0; qq < 8; ++qq) alq[qq] = alpha_lds[(qh << 3) + qq];
#pragma unroll
    for (int di = 0; di < 4; ++di)
#pragma unroll
      for (int qq = 0; qq < 8; ++qq) orun[di][qq] *= alq[qq];

#pragma unroll
    for (int jj = 0; jj < 8; ++jj) {
      int j = (w << 3) + jj;
      const float4 vv = vreg[jj];
      const float4 pa = *(const float4*)&p_lds[j * 20 + (qh << 3)];
      const float4 pb = *(const float4*)&p_lds[j * 20 + (qh << 3) + 4];
      orun[0][0] = fmaf(vv.x, pa.x, orun[0][0]); orun[1][0] = fmaf(vv.y, pa.x, orun[1][0]);
      orun[2][0] = fmaf(vv.z, pa.x, orun[2][0]); orun[3][0] = fmaf(vv.w, pa.x, orun[3][0]);
      orun[0][1] = fmaf(vv.x, pa.y, orun[0][1]); orun[1][1] = fmaf(vv.y, pa.y, orun[1][1]);
      orun[2][1] = fmaf(vv.z, pa.y, orun[2][1]); orun[3][1] = fmaf(vv.w, pa.y, orun[3][1]);
      orun[0][2] = fmaf(vv.x, pa.z, orun[0][2]); orun[1][2] = fmaf(vv.y, pa.z, orun[1][2]);
      orun[2][2] = fmaf(vv.z, pa.z, orun[2][2]); orun[3][2] = fmaf(vv.w, pa.z, orun[3][2]);
      orun[0][3] = fmaf(vv.x, pa.w, orun[0][3]); orun[1][3] = fmaf(vv.y, pa.w, orun[1][3]);
      orun[2][3] = fmaf(vv.z, pa.w, orun[2][3]); orun[3][3] = fmaf(vv.w, pa.w, orun[3][3]);
      orun[0][4] = fmaf(vv.x, pb.x, orun[0][4]); orun[1][4] = fmaf(vv.y, pb.x, orun[1][4]);
      orun[2][4] = fmaf(vv.z, pb.x, orun[2][4]); orun[3][4] = fmaf(vv.w, pb.x, orun[3][4]);
      orun[0][5] = fmaf(vv.x, pb.y, orun[0][5]); orun[1][5] = fmaf(vv.y, pb.y, orun[1][5]);
      orun[2][5] = fmaf(vv.z, pb.y, orun[2][5]); orun[3][5] = fmaf(vv.w, pb.y, orun[3][5]);
      orun[0][6] = fmaf(vv.x, pb.z, orun[0][6]); orun[1][6] = fmaf(vv.y, pb.z, orun[1][6]);
      orun[2][6] = fmaf(vv.z, pb.z, orun[2][6]); orun[3][6] = fmaf(vv.w, pb.z, orun[3][6]);
      orun[0][7] = fmaf(vv.x, pb.w, orun[0][7]); orun[1][7] = fmaf(vv.y, pb.w, orun[1][7]);
      orun[2][7] = fmaf(vv.z, pb.w, orun[2][7]); orun[3][7] = fmaf(vv.w, pb.w, orun[3][7]);
    }
    cur ^= 1;
    __syncthreads();   // PV done before next p/K-buf writes
  }

  // wave-partial o -> LDS (reuse k_lds as o_merge[w][16][128] = 32 KB)
  float* om = &k_lds[0][0];
#pragma unroll
  for (int qq = 0; qq < 8; ++qq) {
    int q = (qh << 3) + qq;
    float4 ov = make_float4(orun[0][qq], orun[1][qq], orun[2][qq], orun[3][qq]);
    *(float4*)&om[(size_t)(((w << 4) + q) << 7) + (dg << 2)] = ov;
  }
  __syncthreads();

  // merge 4 wave-partials -> global split partial
  size_t ob = (size_t)(split * 64 + g) * 2048;
  for (int i = t; i < 2048; i += 256)
    part_o[ob + i] = om[i] + om[i + 2048] + om[i + 4096] + om[i + 6144];
  if (t < 16) {
    part_m[(size_t)(split * 64 + g) * 16 + t] = ml_lds[t];
    part_l[(size_t)(split * 64 + g) * 16 + t] = ml_lds[16 + t];
  }
}

// ---------------------------------------------------------------------------
// Kernel D: combine seq-split partials -> attn_out (32 x 4096, head-major)
// ---------------------------------------------------------------------------
__global__ __launch_bounds__(256) void attn_combine(
    const float* __restrict__ part_o, const float* __restrict__ part_m,
    const float* __restrict__ part_l, float* __restrict__ attn_out) {
  int idx = blockIdx.x * 256 + threadIdx.x;  // 131072
  int d = idx & 127;
  int qi = (idx >> 7) & 15;
  int g = idx >> 11;
  int b = g >> 3, kv = g & 7;
  float M = -NEG_BIG;
#pragma unroll 4
  for (int s = 0; s < NSPLIT; ++s) M = fmaxf(M, part_m[(size_t)(s * 64 + g) * 16 + qi]);
  float osum = 0.f, L = 0.f;
#pragma unroll 4
  for (int s = 0; s < NSPLIT; ++s) {
    size_t ml = (size_t)(s * 64 + g) * 16 + qi;
    float wgt = __expf(part_m[ml] - M);
    osum += part_o[ml * 128 + d] * wgt;
    L += part_l[ml] * wgt;
  }
  int qp = qi >> 2, gi = qi & 3;
  attn_out[(size_t)((b << 2) + qp) * NQCOL + (((kv << 2) + gi) << 7) + d] = osum / L;
}

// ---------------------------------------------------------------------------
// Kernel F: reduce O-proj partials -> d_out
// ---------------------------------------------------------------------------
__global__ __launch_bounds__(256) void reduce_out(
    const float* __restrict__ opart, float* __restrict__ out) {
  int idx = blockIdx.x * 256 + threadIdx.x;  // 131072
  int c = idx & 4095;
  int r = idx >> 12;
  float s = 0.f;
#pragma unroll
  for (int kb = 0; kb < KSPLIT; ++kb)
    s += opart[(size_t)((kb << 5) + r) * NQCOL + c];
  out[idx] = s;
}

extern "C" void kernel_launch(void* const* d_in, const int* in_sizes, int n_in,
                              void* d_out, int out_size, void* d_ws, size_t ws_size,
                              hipStream_t stream) {
  const float* hidden = (const float*)d_in[0];
  const float* cosb   = (const float*)d_in[1];
  const float* sinb   = (const float*)d_in[2];
  const float* Wq     = (const float*)d_in[3];
  const float* Wk     = (const float*)d_in[4];
  const float* Wv     = (const float*)d_in[5];
  const float* Wo     = (const float*)d_in[6];
  float* K_cache      = (float*)d_in[7];
  float* V_cache      = (float*)d_in[8];
  const int* cache_lens = (const int*)d_in[9];
  float* out = (float*)d_out;

  // buf0 (aliased): ypart (32*32*6144 = 6.29M f, the max) -> part_o
  // (33*64*2048 = 4.33M f) -> opart (32*32*4096 = 4.19M f).  Total ws 26.5MB.
  const size_t BUF0 = (size_t)KSPLIT * ROWS * NTOTC;  // 6291456 floats
  float* buf0     = (float*)d_ws;
  float* q_buf    = buf0 + BUF0;                      // 131072
  float* part_m   = q_buf + (size_t)ROWS * NQCOL;     // 33*64*16
  float* part_l   = part_m + (size_t)NSPLIT * 64 * 16;
  float* attn_out = part_l + (size_t)NSPLIT * 64 * 16;  // 131072

  // A: QKV projection partials (512 cols/block)
  gemm32_part<true><<<(NTOTC / 512) * KSPLIT, 256, 0, stream>>>(
      hidden, Wq, Wk, Wv, NQCOL, NQCOL + NKCOL, NTOTC, buf0);
  // B: reduce + RoPE + scatter
  rope_reduce_scatter<<<448, 256, 0, stream>>>(
      buf0, cosb, sinb, cache_lens, q_buf, K_cache, V_cache);
  // C: attention partials (33 splits x 64 groups)
  attn_partial<<<64 * NSPLIT, 256, 0, stream>>>(
      q_buf, K_cache, V_cache, cache_lens, buf0, part_m, part_l);
  // D: combine
  attn_combine<<<512, 256, 0, stream>>>(buf0, part_m, part_l, attn_out);
  // E: O projection partials (256 cols/block)
  gemm32_part<false><<<(NQCOL / 256) * KSPLIT, 256, 0, stream>>>(
      attn_out, Wo, Wo, Wo, NQCOL, NQCOL, NQCOL, buf0);
  // F: reduce to output
  reduce_out<<<512, 256, 0, stream>>>(buf0, out);
}